// Round 11
// baseline (107.121 us; speedup 1.0000x reference)
//
#include <hip/hip_runtime.h>

// Problem geometry (fixed by the reference): u is (B=2, C=3, D=160, H=192, W=160) float32.
#define Dd 160
#define Hh 192
#define Ww 160
#define HW (Hh * Ww)                       // 30720
#define DHW ((size_t)Dd * HW)              // 4,915,200
#define NVOX_D 9830400.0                   // 2 * 160*192*160

// 2 rows/thread: h-pair neighbors in registers, w-edges via shfl.
// VMEM: 12 float4 per 8 voxels (1.5/vox) vs R5's 15 inst per 4 voxels.
#define TH 16                               // h-rows per block (2 per thread)
#define TD 5                                // d-planes per block (sliding window)
#define QROW (Ww / 4)                       // 40 float4-quads per row
#define TPB (QROW * 8)                      // 320 threads = 5 waves
#define NHT (Hh / TH)                       // 12
#define NDS (Dd / TD)                       // 32
#define GRID1 (2 * NHT * NDS)               // 768 blocks = 3 per CU, 8*96
#define NXCD 8
#define CHUNK (GRID1 / NXCD)                // 96
#define NWAVE (TPB / 64)                    // 5
#define BLK2 256

__device__ __forceinline__ float4 ld4(const float* p) {
    return *reinterpret_cast<const float4*>(p);
}

__device__ __forceinline__ int clampi(int v, int lo, int hi) {
    return (v < lo) ? lo : ((v > hi) ? hi : v);
}

// (a - b) * s, componentwise
__device__ __forceinline__ float4 d4(float4 a, float4 b, float s) {
    return make_float4((a.x - b.x) * s, (a.y - b.y) * s,
                       (a.z - b.z) * s, (a.w - b.w) * s);
}

// w-gradient for a quad given its left/right edge scalars (jnp.gradient semantics)
__device__ __forceinline__ float4 wgrad(float4 cc, float lft, float rgt, int w0) {
    float4 g;
    g.x = (w0 == 0)      ? (cc.y - cc.x) : 0.5f * (cc.y - lft);
    g.y = 0.5f * (cc.z - cc.x);
    g.z = 0.5f * (cc.w - cc.y);
    g.w = (w0 + 4 == Ww) ? (cc.w - cc.z) : 0.5f * (rgt - cc.z);
    return g;
}

// relu(-det(J)) for one voxel given the 9 raw (unscaled) finite-difference grads.
__device__ __forceinline__ float relu_negdet(
    float gd0, float gh0, float gw0,
    float gd1, float gh1, float gw1,
    float gd2, float gh2, float gw2)
{
    const float sx = 79.5f;   // (D-1)/2 -> channel 0
    const float sy = 95.5f;   // (H-1)/2 -> channel 1
    const float sz = 79.5f;   // (W-1)/2 -> channel 2
    float dxx = fmaf(sx, gd0, 1.0f);
    float dxy = sx * gh0;
    float dxz = sx * gw0;
    float dyx = sy * gd1;
    float dyy = fmaf(sy, gh1, 1.0f);
    float dyz = sy * gw1;
    float dzx = sz * gd2;
    float dzy = sz * gh2;
    float dzz = fmaf(sz, gw2, 1.0f);
    float det = dxx * (dyy * dzz - dyz * dzy)
              + dxy * (dyz * dzx - dyx * dzz)
              + dxz * (dyx * dzy - dyy * dzx);
    return fmaxf(-det, 0.0f);
}

// relu(-det) summed over one 4-voxel quad row
__device__ __forceinline__ float row_dets(
    float4 gdA, float4 ghA, float4 gwA,
    float4 gdB, float4 ghB, float4 gwB,
    float4 gdC, float4 ghC, float4 gwC)
{
    return relu_negdet(gdA.x, ghA.x, gwA.x, gdB.x, ghB.x, gwB.x, gdC.x, ghC.x, gwC.x)
         + relu_negdet(gdA.y, ghA.y, gwA.y, gdB.y, ghB.y, gwB.y, gdC.y, ghC.y, gwC.y)
         + relu_negdet(gdA.z, ghA.z, gwA.z, gdB.z, ghB.z, gwB.z, gdC.z, ghC.z, gwC.z)
         + relu_negdet(gdA.w, ghA.w, gwA.w, gdB.w, ghB.w, gwB.w, gdC.w, ghC.w, gwC.w);
}

// 2-rows-per-thread register-sliding d-march, barrier-free.
//  - h-gradient: each row's in-pair neighbor is a register; only 2 halo rows
//    per channel per step are loaded (vs 2 per row before).
//  - w-gradient: edge scalars via __shfl_up/down from the wq-adjacent lane's
//    center quad; only 8 wave-seam threads/block use a predicated scalar load.
//  - d-gradient: 3-plane register window (slide), boustrophedon + XCD swizzle.
__global__ __launch_bounds__(TPB) void jac_partial(const float* __restrict__ u,
                                                   float* __restrict__ part)
{
    const int lg  = (blockIdx.x % NXCD) * CHUNK + blockIdx.x / NXCD;
    const int ds  = lg % NDS;
    const int ht  = (lg / NDS) % NHT;
    const int b   = lg / (NDS * NHT);

    const int tid  = threadIdx.x;
    const int wq   = tid % QROW;
    const int hg   = tid / QROW;              // 0..7
    const int h0   = ht * TH + hg * 2;        // even row of the pair (0..190)
    const int h1   = h0 + 1;                  // odd row (1..191)
    const int w0   = wq * 4;
    const int lane = tid & 63;

    // wave-seam fixups: lane 0/63 whose wq-neighbor sits in another wave
    const bool fixlo = (lane == 0)  && (wq > 0);
    const bool fixhi = (lane == 63) && (wq < QROW - 1);

    // jnp.gradient h-edges: row0's h+1 is always row1 (in regs); row1's h-1 is
    // always row0. Only the outer halos clamp.
    const float hinv0 = (h0 > 0) ? 0.5f : 1.0f;
    const float hinv1 = (h1 < Hh - 1) ? 0.5f : 1.0f;
    const int offm = ((h0 > 0 ? h0 - 1 : 0) - h0) * Ww;             // -Ww or 0
    const int offp = (((h1 < Hh - 1) ? h1 + 1 : Hh - 1) - h0) * Ww; // 2Ww or Ww

    const int d0     = ds * TD;
    const int dir    = (ds & 1) ? -1 : 1;      // boustrophedon
    const int dstart = (dir > 0) ? d0 : d0 + TD - 1;

    const float* pc[3];
    pc[0] = u + (size_t)(b * 3 + 0) * DHW + (size_t)h0 * Ww + w0;
    pc[1] = pc[0] + DHW;
    pc[2] = pc[0] + 2 * DHW;

    // 3-plane register window: p0 = behind, p1 = current, p2 = ahead (per step)
    float4 p0[3][2], p1[3][2], p2[3][2];
    {
        const size_t om = (size_t)clampi(dstart - dir, 0, Dd - 1) * HW;
        const size_t oc = (size_t)dstart * HW;
        #pragma unroll
        for (int ch = 0; ch < 3; ++ch) {
            p0[ch][0] = ld4(pc[ch] + om);       p0[ch][1] = ld4(pc[ch] + om + Ww);
            p1[ch][0] = ld4(pc[ch] + oc);       p1[ch][1] = ld4(pc[ch] + oc + Ww);
        }
    }

    float acc = 0.0f;

    #pragma unroll 2
    for (int i = 0; i < TD; ++i) {
        const int d  = dstart + dir * i;
        const int dn = clampi(d + dir, 0, Dd - 1);
        const float dinvs = (float)dir * ((d > 0 && d < Dd - 1) ? 0.5f : 1.0f);
        const size_t od  = (size_t)d  * HW;
        const size_t odn = (size_t)dn * HW;

        // ---- issue all 12 float4 loads up front ----
        float4 hm[3], hp[3];
        #pragma unroll
        for (int ch = 0; ch < 3; ++ch) {
            hm[ch]    = ld4(pc[ch] + od + offm);    // outer halo above pair
            hp[ch]    = ld4(pc[ch] + od + offp);    // outer halo below pair
            p2[ch][0] = ld4(pc[ch] + odn);          // next-plane centers
            p2[ch][1] = ld4(pc[ch] + odn + Ww);
        }
        // wave-seam w-edge scalars (8 threads/block; exec-masked loads)
        float lf[3][2], rf[3][2];
        if (fixlo) {
            #pragma unroll
            for (int ch = 0; ch < 3; ++ch) {
                lf[ch][0] = (pc[ch] + od)[-1];
                lf[ch][1] = (pc[ch] + od + Ww)[-1];
            }
        }
        if (fixhi) {
            #pragma unroll
            for (int ch = 0; ch < 3; ++ch) {
                rf[ch][0] = (pc[ch] + od)[4];
                rf[ch][1] = (pc[ch] + od + Ww)[4];
            }
        }

        // ---- gradients ----
        float4 gw[3][2], gh[3][2], gd[3][2];
        #pragma unroll
        for (int ch = 0; ch < 3; ++ch) {
            #pragma unroll
            for (int r = 0; r < 2; ++r) {
                float4 cc = p1[ch][r];
                float lft = __shfl_up(cc.w, 1);     // wq-1 lane's .w (same row)
                float rgt = __shfl_down(cc.x, 1);   // wq+1 lane's .x
                if (fixlo) lft = lf[ch][r];
                if (fixhi) rgt = rf[ch][r];
                gw[ch][r] = wgrad(cc, lft, rgt, w0);
                gd[ch][r] = d4(p2[ch][r], p0[ch][r], dinvs);
            }
            gh[ch][0] = d4(p1[ch][1], hm[ch], hinv0);   // row0: h+1 in regs
            gh[ch][1] = d4(hp[ch], p1[ch][0], hinv1);   // row1: h-1 in regs
        }

        // ---- determinants (8 voxels) ----
        acc += row_dets(gd[0][0], gh[0][0], gw[0][0],
                        gd[1][0], gh[1][0], gw[1][0],
                        gd[2][0], gh[2][0], gw[2][0])
             + row_dets(gd[0][1], gh[0][1], gw[0][1],
                        gd[1][1], gh[1][1], gw[1][1],
                        gd[2][1], gh[2][1], gw[2][1]);

        // ---- slide the window ----
        #pragma unroll
        for (int ch = 0; ch < 3; ++ch) {
            p0[ch][0] = p1[ch][0]; p0[ch][1] = p1[ch][1];
            p1[ch][0] = p2[ch][0]; p1[ch][1] = p2[ch][1];
        }
    }

    // deterministic block reduction: wave64 shuffle tree, then 5-word LDS
    #pragma unroll
    for (int off = 32; off > 0; off >>= 1)
        acc += __shfl_down(acc, off, 64);
    __shared__ float sred[NWAVE];
    const int wid = tid >> 6;
    if (lane == 0) sred[wid] = acc;
    __syncthreads();
    if (tid == 0)
        part[lg] = ((sred[0] + sred[1]) + (sred[2] + sred[3])) + sred[4];
}

// 768 partials -> mean. 3 independent loads per thread, f64 fixed-tree reduce
// (deterministic; f64 kills the ~2e8-magnitude sum's rounding concern).
__global__ __launch_bounds__(BLK2) void jac_final(const float* __restrict__ part,
                                                  float* __restrict__ out)
{
    const int t = threadIdx.x;
    double a = (double)part[t] + (double)part[t + 256] + (double)part[t + 512];
    __shared__ double s[BLK2];
    s[t] = a;
    __syncthreads();
    #pragma unroll
    for (int off = BLK2 / 2; off > 0; off >>= 1) {
        if (t < off) s[t] += s[t + off];
        __syncthreads();
    }
    if (t == 0)
        out[0] = (float)(s[0] / NVOX_D);
}

extern "C" void kernel_launch(void* const* d_in, const int* in_sizes, int n_in,
                              void* d_out, int out_size, void* d_ws, size_t ws_size,
                              hipStream_t stream)
{
    const float* u = (const float*)d_in[0];
    float* part = (float*)d_ws;              // 768 floats = 3 KB of scratch

    jac_partial<<<GRID1, TPB, 0, stream>>>(u, part);
    jac_final<<<1, BLK2, 0, stream>>>(part, (float*)d_out);
}

// Round 12
// 37.357 us; speedup vs baseline: 2.8675x; 2.8675x over previous
//
#include <hip/hip_runtime.h>

// Problem geometry (fixed by the reference): u is (B=2, C=3, D=160, H=192, W=160) float32.
#define Dd 160
#define Hh 192
#define Ww 160
#define HW (Hh * Ww)                       // 30720
#define DHW ((size_t)Dd * HW)              // 4,915,200
#define NVOX_D 9830400.0                   // 2 * 160*192*160

#define TH 8                                // h-rows per block
#define TD 10                               // d-planes per block (sliding window)
#define QROW (Ww / 4)                       // 40 float4-quads per row
#define TPB (QROW * TH)                     // 320 threads = 5 waves
#define NHT (Hh / TH)                       // 24
#define NDS (Dd / TD)                       // 16
#define GRID1 (2 * NHT * NDS)               // 768 blocks = 3 per CU, 8*96
#define NXCD 8
#define CHUNK (GRID1 / NXCD)                // 96 logical blocks per XCD
#define NWAVE (TPB / 64)                    // 5
#define BLK2 256

__device__ __forceinline__ float4 ld4(const float* p) {
    return *reinterpret_cast<const float4*>(p);
}

__device__ __forceinline__ int clampi(int v, int lo, int hi) {
    return (v < lo) ? lo : ((v > hi) ? hi : v);
}

// w-gradient for a quad given its left/right edge scalars (jnp.gradient semantics)
__device__ __forceinline__ float4 wgrad(float4 cc, float lft, float rgt, int w0) {
    float4 g;
    g.x = (w0 == 0)      ? (cc.y - cc.x) : 0.5f * (cc.y - lft);
    g.y = 0.5f * (cc.z - cc.x);
    g.z = 0.5f * (cc.w - cc.y);
    g.w = (w0 + 4 == Ww) ? (cc.w - cc.z) : 0.5f * (rgt - cc.z);
    return g;
}

// relu(-det(J)) for one voxel given the 9 raw (unscaled) finite-difference grads.
__device__ __forceinline__ float relu_negdet(
    float gd0, float gh0, float gw0,
    float gd1, float gh1, float gw1,
    float gd2, float gh2, float gw2)
{
    const float sx = 79.5f;   // (D-1)/2 -> channel 0
    const float sy = 95.5f;   // (H-1)/2 -> channel 1
    const float sz = 79.5f;   // (W-1)/2 -> channel 2
    float dxx = fmaf(sx, gd0, 1.0f);
    float dxy = sx * gh0;
    float dxz = sx * gw0;
    float dyx = sy * gd1;
    float dyy = fmaf(sy, gh1, 1.0f);
    float dyz = sy * gw1;
    float dzx = sz * gd2;
    float dzy = sz * gh2;
    float dzz = fmaf(sz, gw2, 1.0f);
    float det = dxx * (dyy * dzz - dyz * dzy)
              + dxy * (dyz * dzx - dyx * dzz)
              + dxz * (dyx * dzy - dyy * dzx);
    return fmaxf(-det, 0.0f);
}

// R5 structure + center-plane pipelining:
//  - 3-plane register window {d-1, d, d+1} is FULLY loaded before step d runs;
//    step d issues plane d+2's centers (consumed next step). The long-latency
//    (L3/HBM) loads thus get a full step of compute x 15 waves/CU of cover.
//  - h-neighbor quads + w-edge scalars stay same-step: they are L1/L2 hits
//    (siblings loaded those rows as centers one step earlier).
//  - No launch_bounds min-wave cap (R10 lesson: the cap forced a spill).
__global__ __launch_bounds__(TPB) void jac_partial(const float* __restrict__ u,
                                                   float* __restrict__ part)
{
    // bijective XCD-chunked swizzle (768 = 8*96, ds fastest): d-neighbors same XCD
    const int lg  = (blockIdx.x % NXCD) * CHUNK + blockIdx.x / NXCD;
    const int ds  = lg % NDS;
    const int ht  = (lg / NDS) % NHT;
    const int b   = lg / (NDS * NHT);

    const int tid = threadIdx.x;
    const int wq  = tid % QROW;
    const int hh  = tid / QROW;
    const int h   = ht * TH + hh;
    const int w0  = wq * 4;

    // jnp.gradient edge handling via clamped indices (one-sided at h=0/H-1)
    const int hm = (h > 0)      ? h - 1 : 0;
    const int hp = (h < Hh - 1) ? h + 1 : Hh - 1;
    const float hinv = 1.0f / (float)(hp - hm);
    const int offm = (hm - h) * Ww;   // 0 or -Ww
    const int offp = (hp - h) * Ww;   // 0 or +Ww

    const int d0     = ds * TD;
    const int dir    = (ds & 1) ? -1 : 1;              // boustrophedon
    const int dstart = (dir > 0) ? d0 : d0 + TD - 1;

    // channel base pointers at (b, c, d=0, h, w0)
    const float* pcA = u + (size_t)(b * 3 + 0) * DHW + (size_t)h * Ww + w0;
    const float* pcB = pcA + DHW;
    const float* pcC = pcA + 2 * DHW;

    // center-plane pipeline: M = d-1, C = d, P = d+1 (loaded), I = d+2 (in flight)
    float4 aM, aC, aP, aI, bM, bC, bP, bI, cM, cC, cP, cI;

    // prologue: fill the full 3-plane window
    {
        const size_t om = (size_t)clampi(dstart - dir, 0, Dd - 1) * HW;
        const size_t oc = (size_t)dstart * HW;
        const size_t op = (size_t)clampi(dstart + dir, 0, Dd - 1) * HW;
        aM = ld4(pcA + om);  aC = ld4(pcA + oc);  aP = ld4(pcA + op);
        bM = ld4(pcB + om);  bC = ld4(pcB + oc);  bP = ld4(pcB + op);
        cM = ld4(pcC + om);  cC = ld4(pcC + oc);  cP = ld4(pcC + op);
    }

    float acc = 0.0f;

    #pragma unroll 2
    for (int i = 0; i < TD; ++i) {
        const int d = dstart + dir * i;
        const float dinvs = (float)dir * ((d > 0 && d < Dd - 1) ? 0.5f : 1.0f);
        const size_t od = (size_t)d * HW;

        const float* pdA = pcA + od;
        const float* pdB = pcB + od;
        const float* pdC = pcC + od;

        // 1) same-step short-latency loads: h-neighbor quads + w-edge scalars
        float4 rAm = ld4(pdA + offm), rAp = ld4(pdA + offp);
        float4 rBm = ld4(pdB + offm), rBp = ld4(pdB + offp);
        float4 rCm = ld4(pdC + offm), rCp = ld4(pdC + offp);
        float lA = (w0 > 0) ? pdA[-1] : 0.0f;
        float lB = (w0 > 0) ? pdB[-1] : 0.0f;
        float lC = (w0 > 0) ? pdC[-1] : 0.0f;
        float rA = (w0 + 4 < Ww) ? pdA[4] : 0.0f;
        float rB = (w0 + 4 < Ww) ? pdB[4] : 0.0f;
        float rC = (w0 + 4 < Ww) ? pdC[4] : 0.0f;

        // 2) issue NEXT-next plane centers (d + 2*dir), consumed next iteration
        {
            const size_t oi = (size_t)clampi(d + 2 * dir, 0, Dd - 1) * HW;
            aI = ld4(pcA + oi);
            bI = ld4(pcB + oi);
            cI = ld4(pcC + oi);
        }

        // 3) compute plane d; gd reads ONLY registers (aM/aP loaded >= 1 step ago)
        float4 gwA = wgrad(aC, lA, rA, w0);
        float4 gwB = wgrad(bC, lB, rB, w0);
        float4 gwC = wgrad(cC, lC, rC, w0);

        float4 ghA = make_float4((rAp.x - rAm.x) * hinv, (rAp.y - rAm.y) * hinv,
                                 (rAp.z - rAm.z) * hinv, (rAp.w - rAm.w) * hinv);
        float4 ghB = make_float4((rBp.x - rBm.x) * hinv, (rBp.y - rBm.y) * hinv,
                                 (rBp.z - rBm.z) * hinv, (rBp.w - rBm.w) * hinv);
        float4 ghC = make_float4((rCp.x - rCm.x) * hinv, (rCp.y - rCm.y) * hinv,
                                 (rCp.z - rCm.z) * hinv, (rCp.w - rCm.w) * hinv);

        float4 gdA = make_float4((aP.x - aM.x) * dinvs, (aP.y - aM.y) * dinvs,
                                 (aP.z - aM.z) * dinvs, (aP.w - aM.w) * dinvs);
        float4 gdB = make_float4((bP.x - bM.x) * dinvs, (bP.y - bM.y) * dinvs,
                                 (bP.z - bM.z) * dinvs, (bP.w - bM.w) * dinvs);
        float4 gdC = make_float4((cP.x - cM.x) * dinvs, (cP.y - cM.y) * dinvs,
                                 (cP.z - cM.z) * dinvs, (cP.w - cM.w) * dinvs);

        acc += relu_negdet(gdA.x, ghA.x, gwA.x, gdB.x, ghB.x, gwB.x, gdC.x, ghC.x, gwC.x)
             + relu_negdet(gdA.y, ghA.y, gwA.y, gdB.y, ghB.y, gwB.y, gdC.y, ghC.y, gwC.y)
             + relu_negdet(gdA.z, ghA.z, gwA.z, gdB.z, ghB.z, gwB.z, gdC.z, ghC.z, gwC.z)
             + relu_negdet(gdA.w, ghA.w, gwA.w, gdB.w, ghB.w, gwB.w, gdC.w, ghC.w, gwC.w);

        // 4) slide the pipeline (the wait on aI/bI/cI lands next iteration)
        aM = aC; aC = aP; aP = aI;
        bM = bC; bC = bP; bP = bI;
        cM = cC; cC = cP; cP = cI;
    }

    // deterministic block reduction: wave64 shuffle tree, then 5-word LDS
    #pragma unroll
    for (int off = 32; off > 0; off >>= 1)
        acc += __shfl_down(acc, off, 64);
    __shared__ float sred[NWAVE];
    const int lane = tid & 63;
    const int wid  = tid >> 6;
    if (lane == 0) sred[wid] = acc;
    __syncthreads();
    if (tid == 0)
        part[lg] = ((sred[0] + sred[1]) + (sred[2] + sred[3])) + sred[4];
}

// 768 partials -> mean. 3 independent loads per thread, f64 fixed-tree reduce
// (deterministic; f64 kills the ~2e8-magnitude sum's rounding concern).
__global__ __launch_bounds__(BLK2) void jac_final(const float* __restrict__ part,
                                                  float* __restrict__ out)
{
    const int t = threadIdx.x;
    double a = (double)part[t] + (double)part[t + 256] + (double)part[t + 512];
    __shared__ double s[BLK2];
    s[t] = a;
    __syncthreads();
    #pragma unroll
    for (int off = BLK2 / 2; off > 0; off >>= 1) {
        if (t < off) s[t] += s[t + off];
        __syncthreads();
    }
    if (t == 0)
        out[0] = (float)(s[0] / NVOX_D);
}

extern "C" void kernel_launch(void* const* d_in, const int* in_sizes, int n_in,
                              void* d_out, int out_size, void* d_ws, size_t ws_size,
                              hipStream_t stream)
{
    const float* u = (const float*)d_in[0];
    float* part = (float*)d_ws;              // 768 floats = 3 KB of scratch

    jac_partial<<<GRID1, TPB, 0, stream>>>(u, part);
    jac_final<<<1, BLK2, 0, stream>>>(part, (float*)d_out);
}